// Round 13
// baseline (404.522 us; speedup 1.0000x reference)
//
#include <hip/hip_runtime.h>

#define N_NODES 50000
#define N_EDGES 640000
#define HID 128
#define EDGE_DIM 32
#define NUM_GRAPHS 512
#define BN_EPS 1e-5f
#define NGRP16 3125    // N_NODES / 16 (exact)
#define NSCB 49        // ceil(N_NODES/1024)

typedef unsigned int uint32;
typedef unsigned long long uint64;
typedef unsigned short ushort;
typedef __attribute__((ext_vector_type(8))) short short8;   // 8 bf16 (4 VGPR)
typedef __attribute__((ext_vector_type(4))) float f32x4;    // MFMA accum

// round-to-nearest-even f32 -> bf16 bits
__device__ inline ushort f2bf(float x) {
    uint32 u = __float_as_uint(x);
    return (ushort)((u + 0x7fff + ((u >> 16) & 1)) >> 16);
}

// ---------------------------------------------------------------------------
// Merged preprocessing: blocks [0,2500) histogram deg; blocks [2500,2530)
// pack the 3 layers' weights into MFMA fragment layout.
// B frag: lane l holds B[k][n], n = nt*16 + (l&15), k = kb*32 + (l>>4)*8 + j.
// ---------------------------------------------------------------------------
__global__ __launch_bounds__(256) void pre_kernel(
        const int* __restrict__ eidx, int* __restrict__ deg,
        const float* __restrict__ Wn0, const float* __restrict__ We0,
        const float* __restrict__ Wn1, const float* __restrict__ We1,
        const float* __restrict__ Wn2, const float* __restrict__ We2,
        short8* __restrict__ Wnp0, short8* __restrict__ Wep0,
        short8* __restrict__ Wnp1, short8* __restrict__ Wep1,
        short8* __restrict__ Wnp2, short8* __restrict__ Wep2) {
    int b = blockIdx.x;
    if (b < 2500) {
        int e = b * 256 + threadIdx.x;          // N_EDGES = 2500*256 exactly
        atomicAdd(&deg[eidx[N_EDGES + e]], 1);
        return;
    }
    int idx = b - 2500;                          // 0..29
    int layer = idx / 10;
    int t = (idx % 10) * 256 + threadIdx.x;      // 0..2559
    const float* Wn = (layer == 0) ? Wn0 : (layer == 1) ? Wn1 : Wn2;
    const float* We = (layer == 0) ? We0 : (layer == 1) ? We1 : We2;
    short8* Wnp = (layer == 0) ? Wnp0 : (layer == 1) ? Wnp1 : Wnp2;
    short8* Wep = (layer == 0) ? Wep0 : (layer == 1) ? Wep1 : Wep2;
    if (t < 2048) {
        int l = t & 63, rest = t >> 6;
        int kb = rest & 3, nt = rest >> 2;
        int col = nt * 16 + (l & 15);
        int k0 = kb * 32 + (l >> 4) * 8;
        short8 v;
        #pragma unroll
        for (int j = 0; j < 8; ++j) v[j] = (short)f2bf(Wn[(k0 + j) * 128 + col]);
        Wnp[t] = v;
    } else if (t < 2560) {
        int e = t - 2048;
        int l = e & 63, nt = e >> 6;
        int col = nt * 16 + (l & 15);
        int k0 = (l >> 4) * 8;
        short8 v;
        #pragma unroll
        for (int j = 0; j < 8; ++j) v[j] = (short)f2bf(We[(k0 + j) * 128 + col]);
        Wep[e] = v;
    }
}

// ---------------------------------------------------------------------------
// One-dispatch exclusive scan: each block redundantly sums deg[0 .. b*1024)
// (L2-hot, ~25K ints max) for its base, then scans its own 1024-chunk.
// ---------------------------------------------------------------------------
__global__ __launch_bounds__(256) void scan_kernel(const int* __restrict__ deg,
                                                   int* __restrict__ rowp) {
    __shared__ int red[256];
    int b = blockIdx.x, tid = threadIdx.x;
    // block base = sum of all deg before this chunk
    int pre = 0;
    int limit = b * 1024;
    for (int i = tid; i < limit; i += 256) pre += deg[i];
    red[tid] = pre;
    __syncthreads();
    for (int off = 128; off > 0; off >>= 1) {
        if (tid < off) red[tid] += red[tid + off];
        __syncthreads();
    }
    int base = red[0];
    __syncthreads();
    // local scan of chunk
    int basei = b * 1024 + tid * 4;
    int v[4];
    int s = 0;
    #pragma unroll
    for (int j = 0; j < 4; ++j) {
        int i = basei + j;
        v[j] = (i < N_NODES) ? deg[i] : 0;
        s += v[j];
    }
    red[tid] = s;
    __syncthreads();
    for (int off = 1; off < 256; off <<= 1) {
        int t = (tid >= off) ? red[tid - off] : 0;
        __syncthreads();
        red[tid] += t;
        __syncthreads();
    }
    int excl = base + red[tid] - s;
    #pragma unroll
    for (int j = 0; j < 4; ++j) {
        int i = basei + j;
        if (i < N_NODES) rowp[i] = excl;
        excl += v[j];
    }
    if (b == 0 && tid == 0) rowp[N_NODES] = N_EDGES;
}

// ---------------------------------------------------------------------------
// CSR fill (packed): csr_pk[p] = (eid << 32) | src — one 8B scatter per edge
// ---------------------------------------------------------------------------
__global__ void fill_csr_kernel(const int* __restrict__ eidx,
                                const int* __restrict__ rowp,
                                int* __restrict__ cursor,
                                uint64* __restrict__ csr_pk) {
    int e = blockIdx.x * 256 + threadIdx.x;
    if (e >= N_EDGES) return;
    int d = eidx[N_EDGES + e];
    int pos = rowp[d] + atomicAdd(&cursor[d], 1);
    csr_pk[pos] = ((uint64)(uint32)e << 32) | (uint32)eidx[e];
}

// ---------------------------------------------------------------------------
// Eab[d] = bf16( sum of edge_attr rows with dst == d )   (GEMM A-operand)
// ---------------------------------------------------------------------------
__global__ __launch_bounds__(256) void ea_gather_kernel(
        const float* __restrict__ edge_attr,
        const int* __restrict__ rowp,
        const uint64* __restrict__ csr_pk,
        ushort* __restrict__ Eab) {
    int node = blockIdx.x * 8 + (threadIdx.x >> 5);
    int c = threadIdx.x & 31;
    if (node >= N_NODES) return;
    int beg = rowp[node], end = rowp[node + 1];
    float s0 = 0.f, s1 = 0.f, s2 = 0.f, s3 = 0.f;
    int p = beg;
    for (; p + 4 <= end; p += 4) {
        int e0 = (int)(csr_pk[p]     >> 32);
        int e1 = (int)(csr_pk[p + 1] >> 32);
        int e2 = (int)(csr_pk[p + 2] >> 32);
        int e3 = (int)(csr_pk[p + 3] >> 32);
        s0 += edge_attr[e0 * EDGE_DIM + c];
        s1 += edge_attr[e1 * EDGE_DIM + c];
        s2 += edge_attr[e2 * EDGE_DIM + c];
        s3 += edge_attr[e3 * EDGE_DIM + c];
    }
    for (; p < end; ++p)
        s0 += edge_attr[(int)(csr_pk[p] >> 32) * EDGE_DIM + c];
    Eab[node * EDGE_DIM + c] = f2bf((s0 + s1) + (s2 + s3));
}

// ---------------------------------------------------------------------------
// MFMA GEMM with self-computed BN (scale/shift derived from csq in LDS).
//   xin    = BN ? relu(X*scale + shift) : X      (fp32, cast to bf16 in-reg)
//   h[i]   = xin[i] @ Wn + bn                 -> bf16 h16 (gather operand)
//   acc[i] = h[i] + Ea[i] @ We + deg[i]*be    -> fp32
// csq = previous layer's column {sum[128], sumsq[128]}.
// NOTE: BN-prep barrier happens BEFORE the wave-uniform early exit.
// ---------------------------------------------------------------------------
template <bool BN>
__global__ __launch_bounds__(256) void gemm_mfma_kernel(
        const float* __restrict__ X, const short8* __restrict__ Wnp,
        const float* __restrict__ bnb,
        const ushort* __restrict__ eab, const short8* __restrict__ Wep,
        const float* __restrict__ be, const int* __restrict__ deg,
        const float* __restrict__ csq,
        const float* __restrict__ gamma, const float* __restrict__ beta,
        ushort* __restrict__ h16, float* __restrict__ acc) {
    __shared__ __align__(16) float scs[128];
    __shared__ __align__(16) float shs[128];
    const int tid = threadIdx.x;
    if (BN) {
        if (tid < 128) {
            const float invN = 1.0f / (float)N_NODES;
            float mu = csq[tid] * invN;
            float var = csq[128 + tid] * invN - mu * mu;
            float sc = gamma[tid] * rsqrtf(var + BN_EPS);
            scs[tid] = sc;
            shs[tid] = beta[tid] - mu * sc;
        }
        __syncthreads();
    }

    const int wid = tid >> 6, L = tid & 63;
    const int g = blockIdx.x * 4 + wid;
    if (g >= NGRP16) return;                    // wave-uniform exit (after barrier)
    const int r0 = g * 16;
    const int m = L & 15, kq = L >> 4;

    // A fragments: fp32 row r0+m, k = kb*32 + kq*8 .. +8, BN inline, cast bf16
    short8 afr[4];
    const float* xrow = X + (size_t)(r0 + m) * 128 + kq * 8;
    #pragma unroll
    for (int kb = 0; kb < 4; ++kb) {
        float v[8];
        *(float4*)&v[0] = *(const float4*)(xrow + kb * 32);
        *(float4*)&v[4] = *(const float4*)(xrow + kb * 32 + 4);
        if (BN) {
            float s[8], h[8];
            *(float4*)&s[0] = *(const float4*)(scs + kb * 32 + kq * 8);
            *(float4*)&s[4] = *(const float4*)(scs + kb * 32 + kq * 8 + 4);
            *(float4*)&h[0] = *(const float4*)(shs + kb * 32 + kq * 8);
            *(float4*)&h[4] = *(const float4*)(shs + kb * 32 + kq * 8 + 4);
            #pragma unroll
            for (int j = 0; j < 8; ++j)
                v[j] = fmaxf(0.f, v[j] * s[j] + h[j]);
        }
        short8 a;
        #pragma unroll
        for (int j = 0; j < 8; ++j) a[j] = (short)f2bf(v[j]);
        afr[kb] = a;
    }

    f32x4 d[8];
    #pragma unroll
    for (int nt = 0; nt < 8; ++nt) d[nt] = (f32x4)(0.f);

    // node GEMM: K = 128
    #pragma unroll
    for (int kb = 0; kb < 4; ++kb) {
        #pragma unroll
        for (int nt = 0; nt < 8; ++nt) {
            short8 b = Wnp[(nt * 4 + kb) * 64 + L];
            d[nt] = __builtin_amdgcn_mfma_f32_16x16x32_bf16(afr[kb], b, d[nt], 0, 0, 0);
        }
    }

    float bnv[8], bev[8];
    #pragma unroll
    for (int nt = 0; nt < 8; ++nt) {
        bnv[nt] = bnb[nt * 16 + m];
        bev[nt] = be[nt * 16 + m];
    }

    // h = node + bn -> bf16 (h16[row*128+col]: same bytes as gather's packed u32)
    #pragma unroll
    for (int nt = 0; nt < 8; ++nt) {
        #pragma unroll
        for (int i = 0; i < 4; ++i)
            h16[(size_t)(r0 + kq * 4 + i) * 128 + nt * 16 + m] =
                f2bf(d[nt][i] + bnv[nt]);
    }

    // edge GEMM: K = 32 (one step)
    short8 ae = *(const short8*)(eab + (size_t)(r0 + m) * 32 + kq * 8);
    #pragma unroll
    for (int nt = 0; nt < 8; ++nt)
        d[nt] = __builtin_amdgcn_mfma_f32_16x16x32_bf16(ae, Wep[nt * 64 + L], d[nt], 0, 0, 0);

    float dg[4];
    #pragma unroll
    for (int i = 0; i < 4; ++i) dg[i] = (float)deg[r0 + kq * 4 + i];

    #pragma unroll
    for (int nt = 0; nt < 8; ++nt) {
        #pragma unroll
        for (int i = 0; i < 4; ++i)
            acc[(size_t)(r0 + kq * 4 + i) * 128 + nt * 16 + m] =
                d[nt][i] + bnv[nt] + dg[i] * bev[nt];
    }
}

// ---------------------------------------------------------------------------
// acc[d] += sum over CSR edges of h_bf16[src]
// one WAVE per node; lane covers cols (2*lane, 2*lane+1); 8-deep MLP
// ---------------------------------------------------------------------------
__global__ __launch_bounds__(256) void gather_kernel(
        const uint32* __restrict__ h32,      // 64 uints (=128 bf16) per row
        const int* __restrict__ rowp, const uint64* __restrict__ csr_pk,
        float* __restrict__ acc) {
    int node = blockIdx.x * 4 + (threadIdx.x >> 6);
    if (node >= N_NODES) return;
    int lane = threadIdx.x & 63;
    int beg = rowp[node], end = rowp[node + 1];
    float sx[8] = {0.f,0.f,0.f,0.f,0.f,0.f,0.f,0.f};
    float sy[8] = {0.f,0.f,0.f,0.f,0.f,0.f,0.f,0.f};
    int p = beg;
    for (; p + 8 <= end; p += 8) {
        uint32 v[8];
        #pragma unroll
        for (int j = 0; j < 8; ++j)
            v[j] = h32[(int)(uint32)csr_pk[p + j] * 64 + lane];
        #pragma unroll
        for (int j = 0; j < 8; ++j) {
            sx[j] += __uint_as_float(v[j] << 16);
            sy[j] += __uint_as_float(v[j] & 0xffff0000u);
        }
    }
    for (; p + 4 <= end; p += 4) {
        uint32 v[4];
        #pragma unroll
        for (int j = 0; j < 4; ++j)
            v[j] = h32[(int)(uint32)csr_pk[p + j] * 64 + lane];
        #pragma unroll
        for (int j = 0; j < 4; ++j) {
            sx[j] += __uint_as_float(v[j] << 16);
            sy[j] += __uint_as_float(v[j] & 0xffff0000u);
        }
    }
    for (; p < end; ++p) {
        uint32 v = h32[(int)(uint32)csr_pk[p] * 64 + lane];
        sx[0] += __uint_as_float(v << 16);
        sy[0] += __uint_as_float(v & 0xffff0000u);
    }
    float2* ap = (float2*)&acc[node * 128 + lane * 2];
    float2 a = *ap;
    a.x += ((sx[0] + sx[1]) + (sx[2] + sx[3])) + ((sx[4] + sx[5]) + (sx[6] + sx[7]));
    a.y += ((sy[0] + sy[1]) + (sy[2] + sy[3])) + ((sy[4] + sy[5]) + (sy[6] + sy[7]));
    *ap = a;
}

// per-column sum / sumsq over all nodes -> csq[0:128]=sum, csq[128:256]=sumsq
__global__ void stats_kernel(const float* __restrict__ acc,
                             float* __restrict__ csq) {
    int c = threadIdx.x & 127;
    int rg = threadIdx.x >> 7;
    float s = 0.f, q = 0.f;
    for (int r = blockIdx.x * 2 + rg; r < N_NODES; r += gridDim.x * 2) {
        float v = acc[r * 128 + c];
        s += v; q += v * v;
    }
    unsafeAtomicAdd(&csq[c], s);
    unsafeAtomicAdd(&csq[128 + c], q);
}

// ---------------------------------------------------------------------------
// One block per graph (batch is sorted): binary-search node range, compute
// layer-3 BN scale/shift inline from csq, mean-pool, 128->2 FC. No atomics.
// ---------------------------------------------------------------------------
__global__ __launch_bounds__(256) void pool_fc_kernel(
        const float* __restrict__ acc,
        const float* __restrict__ csq,
        const float* __restrict__ gamma, const float* __restrict__ beta,
        const int* __restrict__ batch,
        const float* __restrict__ Wfc, const float* __restrict__ bfc,
        float* __restrict__ out) {
    __shared__ float ps[256];
    int g = blockIdx.x;
    int lo = 0, hi = N_NODES;
    while (lo < hi) { int mid = (lo + hi) >> 1; if (batch[mid] < g) lo = mid + 1; else hi = mid; }
    int start = lo;
    hi = N_NODES;
    while (lo < hi) { int mid = (lo + hi) >> 1; if (batch[mid] < g + 1) lo = mid + 1; else hi = mid; }
    int end = lo;

    int c = threadIdx.x & 127;
    int half = threadIdx.x >> 7;
    const float invN = 1.0f / (float)N_NODES;
    float mu = csq[c] * invN;
    float var = csq[128 + c] * invN - mu * mu;
    float sc = gamma[c] * rsqrtf(var + BN_EPS);
    float sh = beta[c] - mu * sc;
    float s = 0.f;
    for (int r = start + half; r < end; r += 2)
        s += fmaxf(0.f, acc[r * 128 + c] * sc + sh);
    ps[threadIdx.x] = s;
    __syncthreads();
    if (half == 0)
        ps[c] = (ps[c] + ps[c + 128]) / fmaxf((float)(end - start), 1.0f);
    __syncthreads();
    if (threadIdx.x < 2) {
        int o = threadIdx.x;
        float t = 0.f;
        #pragma unroll 16
        for (int cc = 0; cc < 128; ++cc) t += ps[cc] * Wfc[cc * 2 + o];
        out[g * 2 + o] = t + bfc[o];
    }
}

// ---------------------------------------------------------------------------
extern "C" void kernel_launch(void* const* d_in, const int* in_sizes, int n_in,
                              void* d_out, int out_size, void* d_ws, size_t ws_size,
                              hipStream_t stream) {
    const float* x         = (const float*)d_in[0];
    const float* edge_attr = (const float*)d_in[1];
    const int*   eidx      = (const int*)d_in[2];
    const int*   batch     = (const int*)d_in[3];
    const float* Wn[3]  = {(const float*)d_in[4],  (const float*)d_in[8],  (const float*)d_in[12]};
    const float* bnb[3] = {(const float*)d_in[5],  (const float*)d_in[9],  (const float*)d_in[13]};
    const float* We[3]  = {(const float*)d_in[6],  (const float*)d_in[10], (const float*)d_in[14]};
    const float* be[3]  = {(const float*)d_in[7],  (const float*)d_in[11], (const float*)d_in[15]};
    const float* gm[3]  = {(const float*)d_in[16], (const float*)d_in[18], (const float*)d_in[20]};
    const float* bt[3]  = {(const float*)d_in[17], (const float*)d_in[19], (const float*)d_in[21]};
    const float* Wfc = (const float*)d_in[22];
    const float* bfc = (const float*)d_in[23];
    float* out = (float*)d_out;

    char* p = (char*)d_ws;
    auto alloc = [&](size_t bytes) {
        char* q = p;
        p += (bytes + 255) & ~size_t(255);
        return q;
    };
    // --- zero-region: deg, cursor, csq must stay contiguous (single memset) ---
    int*    deg    = (int*)alloc(sizeof(int) * N_NODES);
    int*    cursor = (int*)alloc(sizeof(int) * N_NODES);
    float*  csq    = (float*)alloc(sizeof(float) * 3 * 256);   // per-layer {sum,sumsq}
    size_t  zbytes = (size_t)((char*)csq + sizeof(float) * 3 * 256 - (char*)deg);
    // --- rest ---
    ushort* h16    = (ushort*)alloc(sizeof(ushort) * N_NODES * HID);      // bf16 h
    ushort* Eab    = (ushort*)alloc(sizeof(ushort) * N_NODES * EDGE_DIM); // bf16 Ea
    float*  accA   = (float*)alloc(sizeof(float) * N_NODES * HID);
    float*  accB   = (float*)alloc(sizeof(float) * N_NODES * HID);
    int*    rowp   = (int*)alloc(sizeof(int) * (N_NODES + 1));
    uint64* csr_pk = (uint64*)alloc(sizeof(uint64) * N_EDGES);
    short8* Wnp[3]; short8* Wep[3];
    for (int l = 0; l < 3; ++l) {
        Wnp[l] = (short8*)alloc(sizeof(short8) * 2048);
        Wep[l] = (short8*)alloc(sizeof(short8) * 512);
    }

    hipMemsetAsync(deg, 0, zbytes, stream);

    pre_kernel<<<2530, 256, 0, stream>>>(eidx, deg,
        Wn[0], We[0], Wn[1], We[1], Wn[2], We[2],
        Wnp[0], Wep[0], Wnp[1], Wep[1], Wnp[2], Wep[2]);
    scan_kernel<<<NSCB, 256, 0, stream>>>(deg, rowp);
    fill_csr_kernel<<<(N_EDGES + 255) / 256, 256, 0, stream>>>(eidx, rowp, cursor, csr_pk);
    ea_gather_kernel<<<(N_NODES + 7) / 8, 256, 0, stream>>>(edge_attr, rowp, csr_pk, Eab);

    float* accs[3] = {accA, accB, accA};
    for (int l = 0; l < 3; ++l) {
        float* acc = accs[l];
        const float* Xin = (l == 0) ? x : accs[l - 1];
        if (l == 0) {
            gemm_mfma_kernel<false><<<(NGRP16 + 3) / 4, 256, 0, stream>>>(
                Xin, Wnp[l], bnb[l], Eab, Wep[l], be[l], deg,
                nullptr, nullptr, nullptr, h16, acc);
        } else {
            gemm_mfma_kernel<true><<<(NGRP16 + 3) / 4, 256, 0, stream>>>(
                Xin, Wnp[l], bnb[l], Eab, Wep[l], be[l], deg,
                csq + (l - 1) * 256, gm[l - 1], bt[l - 1], h16, acc);
        }
        gather_kernel<<<(N_NODES + 3) / 4, 256, 0, stream>>>(
            (const uint32*)h16, rowp, csr_pk, acc);
        stats_kernel<<<256, 256, 0, stream>>>(acc, csq + l * 256);
    }
    pool_fc_kernel<<<NUM_GRAPHS, 256, 0, stream>>>(
        accs[2], csq + 2 * 256, gm[2], bt[2], batch, Wfc, bfc, out);
}

// Round 14
// 402.510 us; speedup vs baseline: 1.0050x; 1.0050x over previous
//
#include <hip/hip_runtime.h>

#define N_NODES 50000
#define N_EDGES 640000
#define HID 128
#define EDGE_DIM 32
#define NUM_GRAPHS 512
#define BN_EPS 1e-5f
#define NGRP16 3125    // N_NODES / 16 (exact)
#define NSCB 49        // ceil(N_NODES/1024)

typedef unsigned int uint32;
typedef unsigned long long uint64;
typedef unsigned short ushort;
typedef __attribute__((ext_vector_type(8))) short short8;   // 8 bf16 (4 VGPR)
typedef __attribute__((ext_vector_type(4))) float f32x4;    // MFMA accum

// round-to-nearest-even f32 -> bf16 bits
__device__ inline ushort f2bf(float x) {
    uint32 u = __float_as_uint(x);
    return (ushort)((u + 0x7fff + ((u >> 16) & 1)) >> 16);
}

// ---------------------------------------------------------------------------
// Merged preprocessing: blocks [0,2500) histogram deg; blocks [2500,2530)
// pack the 3 layers' weights into MFMA fragment layout.
// ---------------------------------------------------------------------------
__global__ __launch_bounds__(256) void pre_kernel(
        const int* __restrict__ eidx, int* __restrict__ deg,
        const float* __restrict__ Wn0, const float* __restrict__ We0,
        const float* __restrict__ Wn1, const float* __restrict__ We1,
        const float* __restrict__ Wn2, const float* __restrict__ We2,
        short8* __restrict__ Wnp0, short8* __restrict__ Wep0,
        short8* __restrict__ Wnp1, short8* __restrict__ Wep1,
        short8* __restrict__ Wnp2, short8* __restrict__ Wep2) {
    int b = blockIdx.x;
    if (b < 2500) {
        int e = b * 256 + threadIdx.x;          // N_EDGES = 2500*256 exactly
        atomicAdd(&deg[eidx[N_EDGES + e]], 1);
        return;
    }
    int idx = b - 2500;                          // 0..29
    int layer = idx / 10;
    int t = (idx % 10) * 256 + threadIdx.x;      // 0..2559
    const float* Wn = (layer == 0) ? Wn0 : (layer == 1) ? Wn1 : Wn2;
    const float* We = (layer == 0) ? We0 : (layer == 1) ? We1 : We2;
    short8* Wnp = (layer == 0) ? Wnp0 : (layer == 1) ? Wnp1 : Wnp2;
    short8* Wep = (layer == 0) ? Wep0 : (layer == 1) ? Wep1 : Wep2;
    if (t < 2048) {
        int l = t & 63, rest = t >> 6;
        int kb = rest & 3, nt = rest >> 2;
        int col = nt * 16 + (l & 15);
        int k0 = kb * 32 + (l >> 4) * 8;
        short8 v;
        #pragma unroll
        for (int j = 0; j < 8; ++j) v[j] = (short)f2bf(Wn[(k0 + j) * 128 + col]);
        Wnp[t] = v;
    } else if (t < 2560) {
        int e = t - 2048;
        int l = e & 63, nt = e >> 6;
        int col = nt * 16 + (l & 15);
        int k0 = (l >> 4) * 8;
        short8 v;
        #pragma unroll
        for (int j = 0; j < 8; ++j) v[j] = (short)f2bf(We[(k0 + j) * 128 + col]);
        Wep[e] = v;
    }
}

// ---------------------------------------------------------------------------
// One-dispatch exclusive scan: each block redundantly sums deg[0 .. b*1024)
// ---------------------------------------------------------------------------
__global__ __launch_bounds__(256) void scan_kernel(const int* __restrict__ deg,
                                                   int* __restrict__ rowp) {
    __shared__ int red[256];
    int b = blockIdx.x, tid = threadIdx.x;
    int pre = 0;
    int limit = b * 1024;
    for (int i = tid; i < limit; i += 256) pre += deg[i];
    red[tid] = pre;
    __syncthreads();
    for (int off = 128; off > 0; off >>= 1) {
        if (tid < off) red[tid] += red[tid + off];
        __syncthreads();
    }
    int base = red[0];
    __syncthreads();
    int basei = b * 1024 + tid * 4;
    int v[4];
    int s = 0;
    #pragma unroll
    for (int j = 0; j < 4; ++j) {
        int i = basei + j;
        v[j] = (i < N_NODES) ? deg[i] : 0;
        s += v[j];
    }
    red[tid] = s;
    __syncthreads();
    for (int off = 1; off < 256; off <<= 1) {
        int t = (tid >= off) ? red[tid - off] : 0;
        __syncthreads();
        red[tid] += t;
        __syncthreads();
    }
    int excl = base + red[tid] - s;
    #pragma unroll
    for (int j = 0; j < 4; ++j) {
        int i = basei + j;
        if (i < N_NODES) rowp[i] = excl;
        excl += v[j];
    }
    if (b == 0 && tid == 0) rowp[N_NODES] = N_EDGES;
}

// ---------------------------------------------------------------------------
// CSR fill (packed): csr_pk[p] = (eid << 32) | src — one 8B scatter per edge
// ---------------------------------------------------------------------------
__global__ void fill_csr_kernel(const int* __restrict__ eidx,
                                const int* __restrict__ rowp,
                                int* __restrict__ cursor,
                                uint64* __restrict__ csr_pk) {
    int e = blockIdx.x * 256 + threadIdx.x;
    if (e >= N_EDGES) return;
    int d = eidx[N_EDGES + e];
    int pos = rowp[d] + atomicAdd(&cursor[d], 1);
    csr_pk[pos] = ((uint64)(uint32)e << 32) | (uint32)eidx[e];
}

// ---------------------------------------------------------------------------
// Eab[d] = bf16( sum of edge_attr rows with dst == d )   (GEMM A-operand)
// ---------------------------------------------------------------------------
__global__ __launch_bounds__(256) void ea_gather_kernel(
        const float* __restrict__ edge_attr,
        const int* __restrict__ rowp,
        const uint64* __restrict__ csr_pk,
        ushort* __restrict__ Eab) {
    int node = blockIdx.x * 8 + (threadIdx.x >> 5);
    int c = threadIdx.x & 31;
    if (node >= N_NODES) return;
    int beg = rowp[node], end = rowp[node + 1];
    float s0 = 0.f, s1 = 0.f, s2 = 0.f, s3 = 0.f;
    int p = beg;
    for (; p + 4 <= end; p += 4) {
        int e0 = (int)(csr_pk[p]     >> 32);
        int e1 = (int)(csr_pk[p + 1] >> 32);
        int e2 = (int)(csr_pk[p + 2] >> 32);
        int e3 = (int)(csr_pk[p + 3] >> 32);
        s0 += edge_attr[e0 * EDGE_DIM + c];
        s1 += edge_attr[e1 * EDGE_DIM + c];
        s2 += edge_attr[e2 * EDGE_DIM + c];
        s3 += edge_attr[e3 * EDGE_DIM + c];
    }
    for (; p < end; ++p)
        s0 += edge_attr[(int)(csr_pk[p] >> 32) * EDGE_DIM + c];
    Eab[node * EDGE_DIM + c] = f2bf((s0 + s1) + (s2 + s3));
}

// ---------------------------------------------------------------------------
// MFMA GEMM with self-computed BN (scale/shift derived from csq in LDS).
// ---------------------------------------------------------------------------
template <bool BN>
__global__ __launch_bounds__(256) void gemm_mfma_kernel(
        const float* __restrict__ X, const short8* __restrict__ Wnp,
        const float* __restrict__ bnb,
        const ushort* __restrict__ eab, const short8* __restrict__ Wep,
        const float* __restrict__ be, const int* __restrict__ deg,
        const float* __restrict__ csq,
        const float* __restrict__ gamma, const float* __restrict__ beta,
        ushort* __restrict__ h16, float* __restrict__ acc) {
    __shared__ __align__(16) float scs[128];
    __shared__ __align__(16) float shs[128];
    const int tid = threadIdx.x;
    if (BN) {
        if (tid < 128) {
            const float invN = 1.0f / (float)N_NODES;
            float mu = csq[tid] * invN;
            float var = csq[128 + tid] * invN - mu * mu;
            float sc = gamma[tid] * rsqrtf(var + BN_EPS);
            scs[tid] = sc;
            shs[tid] = beta[tid] - mu * sc;
        }
        __syncthreads();
    }

    const int wid = tid >> 6, L = tid & 63;
    const int g = blockIdx.x * 4 + wid;
    if (g >= NGRP16) return;                    // wave-uniform exit (after barrier)
    const int r0 = g * 16;
    const int m = L & 15, kq = L >> 4;

    short8 afr[4];
    const float* xrow = X + (size_t)(r0 + m) * 128 + kq * 8;
    #pragma unroll
    for (int kb = 0; kb < 4; ++kb) {
        float v[8];
        *(float4*)&v[0] = *(const float4*)(xrow + kb * 32);
        *(float4*)&v[4] = *(const float4*)(xrow + kb * 32 + 4);
        if (BN) {
            float s[8], h[8];
            *(float4*)&s[0] = *(const float4*)(scs + kb * 32 + kq * 8);
            *(float4*)&s[4] = *(const float4*)(scs + kb * 32 + kq * 8 + 4);
            *(float4*)&h[0] = *(const float4*)(shs + kb * 32 + kq * 8);
            *(float4*)&h[4] = *(const float4*)(shs + kb * 32 + kq * 8 + 4);
            #pragma unroll
            for (int j = 0; j < 8; ++j)
                v[j] = fmaxf(0.f, v[j] * s[j] + h[j]);
        }
        short8 a;
        #pragma unroll
        for (int j = 0; j < 8; ++j) a[j] = (short)f2bf(v[j]);
        afr[kb] = a;
    }

    f32x4 d[8];
    #pragma unroll
    for (int nt = 0; nt < 8; ++nt) d[nt] = (f32x4)(0.f);

    #pragma unroll
    for (int kb = 0; kb < 4; ++kb) {
        #pragma unroll
        for (int nt = 0; nt < 8; ++nt) {
            short8 b = Wnp[(nt * 4 + kb) * 64 + L];
            d[nt] = __builtin_amdgcn_mfma_f32_16x16x32_bf16(afr[kb], b, d[nt], 0, 0, 0);
        }
    }

    float bnv[8], bev[8];
    #pragma unroll
    for (int nt = 0; nt < 8; ++nt) {
        bnv[nt] = bnb[nt * 16 + m];
        bev[nt] = be[nt * 16 + m];
    }

    #pragma unroll
    for (int nt = 0; nt < 8; ++nt) {
        #pragma unroll
        for (int i = 0; i < 4; ++i)
            h16[(size_t)(r0 + kq * 4 + i) * 128 + nt * 16 + m] =
                f2bf(d[nt][i] + bnv[nt]);
    }

    short8 ae = *(const short8*)(eab + (size_t)(r0 + m) * 32 + kq * 8);
    #pragma unroll
    for (int nt = 0; nt < 8; ++nt)
        d[nt] = __builtin_amdgcn_mfma_f32_16x16x32_bf16(ae, Wep[nt * 64 + L], d[nt], 0, 0, 0);

    float dg[4];
    #pragma unroll
    for (int i = 0; i < 4; ++i) dg[i] = (float)deg[r0 + kq * 4 + i];

    #pragma unroll
    for (int nt = 0; nt < 8; ++nt) {
        #pragma unroll
        for (int i = 0; i < 4; ++i)
            acc[(size_t)(r0 + kq * 4 + i) * 128 + nt * 16 + m] =
                d[nt][i] + bnv[nt] + dg[i] * bev[nt];
    }
}

// ---------------------------------------------------------------------------
// acc[d] += sum over CSR edges of h_bf16[src]  — FUSED column stats.
// One wave per node, 4 nodes per wave (grid 3125 x 4 waves x 4 = 50000 exact).
// Wave register-accumulates col sum/sumsq of its nodes' FINAL acc values;
// end-of-kernel LDS cross-wave reduce -> coalesced per-block partial store.
// ---------------------------------------------------------------------------
__global__ __launch_bounds__(256) void gather_kernel(
        const uint32* __restrict__ h32,      // 64 uints (=128 bf16) per row
        const int* __restrict__ rowp, const uint64* __restrict__ csr_pk,
        float* __restrict__ acc, float* __restrict__ partial) {
    __shared__ float red_s[4][128];
    __shared__ float red_q[4][128];
    int wid = threadIdx.x >> 6, lane = threadIdx.x & 63;
    float cs_x = 0.f, cs_y = 0.f, cq_x = 0.f, cq_y = 0.f;
    #pragma unroll
    for (int i = 0; i < 4; ++i) {
        int node = blockIdx.x * 16 + wid * 4 + i;
        int beg = rowp[node], end = rowp[node + 1];
        float sx[8] = {0.f,0.f,0.f,0.f,0.f,0.f,0.f,0.f};
        float sy[8] = {0.f,0.f,0.f,0.f,0.f,0.f,0.f,0.f};
        int p = beg;
        for (; p + 8 <= end; p += 8) {
            uint32 v[8];
            #pragma unroll
            for (int j = 0; j < 8; ++j)
                v[j] = h32[(int)(uint32)csr_pk[p + j] * 64 + lane];
            #pragma unroll
            for (int j = 0; j < 8; ++j) {
                sx[j] += __uint_as_float(v[j] << 16);
                sy[j] += __uint_as_float(v[j] & 0xffff0000u);
            }
        }
        for (; p + 4 <= end; p += 4) {
            uint32 v[4];
            #pragma unroll
            for (int j = 0; j < 4; ++j)
                v[j] = h32[(int)(uint32)csr_pk[p + j] * 64 + lane];
            #pragma unroll
            for (int j = 0; j < 4; ++j) {
                sx[j] += __uint_as_float(v[j] << 16);
                sy[j] += __uint_as_float(v[j] & 0xffff0000u);
            }
        }
        for (; p < end; ++p) {
            uint32 v = h32[(int)(uint32)csr_pk[p] * 64 + lane];
            sx[0] += __uint_as_float(v << 16);
            sy[0] += __uint_as_float(v & 0xffff0000u);
        }
        float2* ap = (float2*)&acc[(size_t)node * 128 + lane * 2];
        float2 a = *ap;
        a.x += ((sx[0] + sx[1]) + (sx[2] + sx[3])) + ((sx[4] + sx[5]) + (sx[6] + sx[7]));
        a.y += ((sy[0] + sy[1]) + (sy[2] + sy[3])) + ((sy[4] + sy[5]) + (sy[6] + sy[7]));
        *ap = a;
        cs_x += a.x; cs_y += a.y;
        cq_x += a.x * a.x; cq_y += a.y * a.y;
    }
    red_s[wid][lane * 2]     = cs_x;
    red_s[wid][lane * 2 + 1] = cs_y;
    red_q[wid][lane * 2]     = cq_x;
    red_q[wid][lane * 2 + 1] = cq_y;
    __syncthreads();
    int t = threadIdx.x;
    if (t < 128) {
        float s = (red_s[0][t] + red_s[1][t]) + (red_s[2][t] + red_s[3][t]);
        partial[(size_t)blockIdx.x * 256 + t] = s;
    } else {
        int c = t - 128;
        float q = (red_q[0][c] + red_q[1][c]) + (red_q[2][c] + red_q[3][c]);
        partial[(size_t)blockIdx.x * 256 + 128 + c] = q;
    }
}

// reduce per-block partials (3125 x 256) -> csq[256]
__global__ __launch_bounds__(256) void stats2_kernel(
        const float* __restrict__ partial, float* __restrict__ csq) {
    int t = threadIdx.x;
    float s = 0.f;
    for (int b = blockIdx.x; b < NGRP16; b += gridDim.x)
        s += partial[(size_t)b * 256 + t];
    unsafeAtomicAdd(&csq[t], s);
}

// ---------------------------------------------------------------------------
// One block per graph (batch is sorted): binary-search node range, compute
// layer-3 BN scale/shift inline from csq, mean-pool, 128->2 FC. No atomics.
// ---------------------------------------------------------------------------
__global__ __launch_bounds__(256) void pool_fc_kernel(
        const float* __restrict__ acc,
        const float* __restrict__ csq,
        const float* __restrict__ gamma, const float* __restrict__ beta,
        const int* __restrict__ batch,
        const float* __restrict__ Wfc, const float* __restrict__ bfc,
        float* __restrict__ out) {
    __shared__ float ps[256];
    int g = blockIdx.x;
    int lo = 0, hi = N_NODES;
    while (lo < hi) { int mid = (lo + hi) >> 1; if (batch[mid] < g) lo = mid + 1; else hi = mid; }
    int start = lo;
    hi = N_NODES;
    while (lo < hi) { int mid = (lo + hi) >> 1; if (batch[mid] < g + 1) lo = mid + 1; else hi = mid; }
    int end = lo;

    int c = threadIdx.x & 127;
    int half = threadIdx.x >> 7;
    const float invN = 1.0f / (float)N_NODES;
    float mu = csq[c] * invN;
    float var = csq[128 + c] * invN - mu * mu;
    float sc = gamma[c] * rsqrtf(var + BN_EPS);
    float sh = beta[c] - mu * sc;
    float s = 0.f;
    for (int r = start + half; r < end; r += 2)
        s += fmaxf(0.f, acc[r * 128 + c] * sc + sh);
    ps[threadIdx.x] = s;
    __syncthreads();
    if (half == 0)
        ps[c] = (ps[c] + ps[c + 128]) / fmaxf((float)(end - start), 1.0f);
    __syncthreads();
    if (threadIdx.x < 2) {
        int o = threadIdx.x;
        float t = 0.f;
        #pragma unroll 16
        for (int cc = 0; cc < 128; ++cc) t += ps[cc] * Wfc[cc * 2 + o];
        out[g * 2 + o] = t + bfc[o];
    }
}

// ---------------------------------------------------------------------------
extern "C" void kernel_launch(void* const* d_in, const int* in_sizes, int n_in,
                              void* d_out, int out_size, void* d_ws, size_t ws_size,
                              hipStream_t stream) {
    const float* x         = (const float*)d_in[0];
    const float* edge_attr = (const float*)d_in[1];
    const int*   eidx      = (const int*)d_in[2];
    const int*   batch     = (const int*)d_in[3];
    const float* Wn[3]  = {(const float*)d_in[4],  (const float*)d_in[8],  (const float*)d_in[12]};
    const float* bnb[3] = {(const float*)d_in[5],  (const float*)d_in[9],  (const float*)d_in[13]};
    const float* We[3]  = {(const float*)d_in[6],  (const float*)d_in[10], (const float*)d_in[14]};
    const float* be[3]  = {(const float*)d_in[7],  (const float*)d_in[11], (const float*)d_in[15]};
    const float* gm[3]  = {(const float*)d_in[16], (const float*)d_in[18], (const float*)d_in[20]};
    const float* bt[3]  = {(const float*)d_in[17], (const float*)d_in[19], (const float*)d_in[21]};
    const float* Wfc = (const float*)d_in[22];
    const float* bfc = (const float*)d_in[23];
    float* out = (float*)d_out;

    char* p = (char*)d_ws;
    auto alloc = [&](size_t bytes) {
        char* q = p;
        p += (bytes + 255) & ~size_t(255);
        return q;
    };
    // --- zero-region: deg, cursor, csq contiguous (single memset) ---
    int*    deg    = (int*)alloc(sizeof(int) * N_NODES);
    int*    cursor = (int*)alloc(sizeof(int) * N_NODES);
    float*  csq    = (float*)alloc(sizeof(float) * 3 * 256);   // per-layer {sum,sumsq}
    size_t  zbytes = (size_t)((char*)csq + sizeof(float) * 3 * 256 - (char*)deg);
    // --- rest ---
    ushort* h16    = (ushort*)alloc(sizeof(ushort) * N_NODES * HID);      // bf16 h
    ushort* Eab    = (ushort*)alloc(sizeof(ushort) * N_NODES * EDGE_DIM); // bf16 Ea
    float*  accA   = (float*)alloc(sizeof(float) * N_NODES * HID);
    float*  accB   = (float*)alloc(sizeof(float) * N_NODES * HID);
    float*  part   = (float*)alloc(sizeof(float) * NGRP16 * 256);         // gather stats partials
    int*    rowp   = (int*)alloc(sizeof(int) * (N_NODES + 1));
    uint64* csr_pk = (uint64*)alloc(sizeof(uint64) * N_EDGES);
    short8* Wnp[3]; short8* Wep[3];
    for (int l = 0; l < 3; ++l) {
        Wnp[l] = (short8*)alloc(sizeof(short8) * 2048);
        Wep[l] = (short8*)alloc(sizeof(short8) * 512);
    }

    hipMemsetAsync(deg, 0, zbytes, stream);

    pre_kernel<<<2530, 256, 0, stream>>>(eidx, deg,
        Wn[0], We[0], Wn[1], We[1], Wn[2], We[2],
        Wnp[0], Wep[0], Wnp[1], Wep[1], Wnp[2], Wep[2]);
    scan_kernel<<<NSCB, 256, 0, stream>>>(deg, rowp);
    fill_csr_kernel<<<(N_EDGES + 255) / 256, 256, 0, stream>>>(eidx, rowp, cursor, csr_pk);
    ea_gather_kernel<<<(N_NODES + 7) / 8, 256, 0, stream>>>(edge_attr, rowp, csr_pk, Eab);

    float* accs[3] = {accA, accB, accA};
    for (int l = 0; l < 3; ++l) {
        float* acc = accs[l];
        const float* Xin = (l == 0) ? x : accs[l - 1];
        if (l == 0) {
            gemm_mfma_kernel<false><<<(NGRP16 + 3) / 4, 256, 0, stream>>>(
                Xin, Wnp[l], bnb[l], Eab, Wep[l], be[l], deg,
                nullptr, nullptr, nullptr, h16, acc);
        } else {
            gemm_mfma_kernel<true><<<(NGRP16 + 3) / 4, 256, 0, stream>>>(
                Xin, Wnp[l], bnb[l], Eab, Wep[l], be[l], deg,
                csq + (l - 1) * 256, gm[l - 1], bt[l - 1], h16, acc);
        }
        gather_kernel<<<NGRP16, 256, 0, stream>>>(
            (const uint32*)h16, rowp, csr_pk, acc, part);
        stats2_kernel<<<25, 256, 0, stream>>>(part, csq + l * 256);
    }
    pool_fc_kernel<<<NUM_GRAPHS, 256, 0, stream>>>(
        accs[2], csq + 2 * 256, gm[2], bt[2], batch, Wfc, bfc, out);
}